// Round 1
// baseline (71.373 us; speedup 1.0000x reference)
//
#include <hip/hip_runtime.h>
#include <math.h>

#define BB 32
#define FF 6
#define NN 1024

// order-preserving float <-> uint mapping (total order, works for +/-)
__device__ __forceinline__ unsigned f2o(float f) {
    unsigned u = __float_as_uint(f);
    return (u & 0x80000000u) ? ~u : (u | 0x80000000u);
}
__device__ __forceinline__ float o2f(unsigned u) {
    return (u & 0x80000000u) ? __uint_as_float(u & 0x7FFFFFFFu)
                             : __uint_as_float(~u);
}

__global__ void k_init(unsigned* __restrict__ wsu) {
    int t = threadIdx.x;
    if (t < BB) wsu[t] = 0xFFFFFFFFu;   // +inf in orderable encoding -> min slot
    if (t == BB) wsu[BB] = 0u;          // -inf in orderable encoding -> max slot
}

// Pass 1: per-batch off-diagonal min of d_ij, global max of d_ij.
// grid = BB*8 blocks (8 chunks of 128 rows per batch), 256 threads (4 waves),
// each wave owns 32 rows.
__global__ __launch_bounds__(256) void k_minmax(const float* __restrict__ emb,
                                                const float* __restrict__ alphap,
                                                unsigned* __restrict__ wsu) {
    __shared__ float s_emb[FF][NN];   // 24 KB
    __shared__ float s_pm[NN];        // 4 KB
    const int b = blockIdx.x >> 3;
    const int chunk = blockIdx.x & 7;
    const int tid = threadIdx.x;

    const float* e = emb + (size_t)b * FF * NN;
    for (int f = 0; f < FF; ++f) {
        const float4* src = (const float4*)(e + f * NN);
        float4* dst = (float4*)(&s_emb[f][0]);
        for (int j = tid; j < NN / 4; j += 256) dst[j] = src[j];
    }
    __syncthreads();
    const float a2 = 2.0f * alphap[0];
    for (int j = tid; j < NN; j += 256) {
        float m = s_emb[4][j];
        s_pm[j] = expf(a2 * logf(m));   // momentum^(2*alpha)
    }
    __syncthreads();

    const int wid = tid >> 6, lane = tid & 63;
    float vmin = 3.4e38f, vmax = 0.0f;

    for (int r = 0; r < 32; ++r) {
        const int i = chunk * 128 + wid * 32 + r;
        float eif[FF];
        #pragma unroll
        for (int f = 0; f < FF; ++f) eif[f] = s_emb[f][i];
        const float pmi = s_pm[i];

        #pragma unroll
        for (int k = 0; k < 4; ++k) {
            const int j0 = lane * 4 + k * 256;
            float4 q[FF];
            #pragma unroll
            for (int f = 0; f < FF; ++f) q[f] = *(const float4*)&s_emb[f][j0];
            float4 pj = *(const float4*)&s_pm[j0];
            #pragma unroll
            for (int c = 0; c < 4; ++c) {
                float acc = 0.0f;
                #pragma unroll
                for (int f = 0; f < FF; ++f) {
                    float t = ((const float*)&q[f])[c] - eif[f];
                    acc = fmaf(t, t, acc);   // sum of squared diffs: no cancellation
                }
                float pmm = fminf(pmi, ((const float*)&pj)[c]);
                float d = acc * pmm;
                vmax = fmaxf(vmax, d);
                int j = j0 + c;
                vmin = (j == i) ? vmin : fminf(vmin, d);
            }
        }
    }
    #pragma unroll
    for (int o = 32; o >= 1; o >>= 1) {
        vmin = fminf(vmin, __shfl_xor(vmin, o));
        vmax = fmaxf(vmax, __shfl_xor(vmax, o));
    }
    if (lane == 0) {
        atomicMin(&wsu[b], f2o(vmin));
        atomicMax(&wsu[BB], f2o(vmax));
    }
}

// Pass 2: recompute d row-by-row in registers, row-softmax, write out.
// grid = BB*32 blocks (chunks of 32 rows), 256 threads = 4 waves, wave owns 8 rows.
__global__ __launch_bounds__(256) void k_softmax(const float* __restrict__ emb,
                                                 const float* __restrict__ alphap,
                                                 const float* __restrict__ betap,
                                                 const unsigned* __restrict__ wsu,
                                                 float* __restrict__ out) {
    __shared__ float s_emb[FF][NN];
    __shared__ float s_pm[NN];
    const int b = blockIdx.x >> 5;
    const int chunk = blockIdx.x & 31;
    const int tid = threadIdx.x;

    const float* e = emb + (size_t)b * FF * NN;
    for (int f = 0; f < FF; ++f) {
        const float4* src = (const float4*)(e + f * NN);
        float4* dst = (float4*)(&s_emb[f][0]);
        for (int j = tid; j < NN / 4; j += 256) dst[j] = src[j];
    }
    __syncthreads();
    const float a2 = 2.0f * alphap[0];
    for (int j = tid; j < NN; j += 256) {
        float m = s_emb[4][j];
        s_pm[j] = expf(a2 * logf(m));
    }
    __syncthreads();

    const float dmin = o2f(wsu[b]);
    const float big  = 1000.0f * o2f(wsu[BB]);
    const float beta = betap[0];
    const float s    = beta * beta / dmin;   // exponent scale

    const int wid = tid >> 6, lane = tid & 63;

    for (int r = 0; r < 8; ++r) {
        const int i = chunk * 32 + wid * 8 + r;
        float eif[FF];
        #pragma unroll
        for (int f = 0; f < FF; ++f) eif[f] = s_emb[f][i];
        const float pmi = s_pm[i];

        float d[16];
        #pragma unroll
        for (int k = 0; k < 4; ++k) {
            const int j0 = lane * 4 + k * 256;
            float4 q[FF];
            #pragma unroll
            for (int f = 0; f < FF; ++f) q[f] = *(const float4*)&s_emb[f][j0];
            float4 pj = *(const float4*)&s_pm[j0];
            #pragma unroll
            for (int c = 0; c < 4; ++c) {
                float acc = 0.0f;
                #pragma unroll
                for (int f = 0; f < FF; ++f) {
                    float t = ((const float*)&q[f])[c] - eif[f];
                    acc = fmaf(t, t, acc);
                }
                float pmm = fminf(pmi, ((const float*)&pj)[c]);
                float dd = acc * pmm;
                if (j0 + c == i) dd = big;   // diagonal gets +big (sqdist_ii = 0)
                d[k * 4 + c] = dd;
            }
        }
        // row min (== -rowmax of d_norm, softmax shift)
        float rmin = d[0];
        #pragma unroll
        for (int t = 1; t < 16; ++t) rmin = fminf(rmin, d[t]);
        #pragma unroll
        for (int o = 32; o >= 1; o >>= 1) rmin = fminf(rmin, __shfl_xor(rmin, o));

        float sum = 0.0f;
        #pragma unroll
        for (int t = 0; t < 16; ++t) {
            float p = __expf(-s * (d[t] - rmin));
            d[t] = p;
            sum += p;
        }
        #pragma unroll
        for (int o = 32; o >= 1; o >>= 1) sum += __shfl_xor(sum, o);
        const float inv = 1.0f / sum;

        float* op = out + ((size_t)(b * NN + i)) * NN;
        #pragma unroll
        for (int k = 0; k < 4; ++k) {
            const int j0 = lane * 4 + k * 256;
            float4 w;
            w.x = d[k * 4 + 0] * inv;
            w.y = d[k * 4 + 1] * inv;
            w.z = d[k * 4 + 2] * inv;
            w.w = d[k * 4 + 3] * inv;
            *(float4*)&op[j0] = w;
        }
    }
}

extern "C" void kernel_launch(void* const* d_in, const int* in_sizes, int n_in,
                              void* d_out, int out_size, void* d_ws, size_t ws_size,
                              hipStream_t stream) {
    const float* emb   = (const float*)d_in[0];
    const float* alpha = (const float*)d_in[1];
    const float* beta  = (const float*)d_in[2];
    float* out = (float*)d_out;
    unsigned* wsu = (unsigned*)d_ws;

    k_init<<<1, 64, 0, stream>>>(wsu);
    k_minmax<<<BB * 8, 256, 0, stream>>>(emb, alpha, wsu);
    k_softmax<<<BB * 32, 256, 0, stream>>>(emb, alpha, beta, wsu, out);
}

// Round 2
// 56.956 us; speedup vs baseline: 1.2531x; 1.2531x over previous
//
#include <hip/hip_runtime.h>
#include <math.h>

#define BB 32
#define FF 6
#define NN 1024

// ---------------------------------------------------------------------------
// Pass 1: per-block partial min of off-diagonal d_ij (upper triangle only).
// grid = BB*32 blocks (32 row-chunks per batch), 256 threads = 4 waves,
// each wave owns 8 rows. j-columns live in REGISTERS (16 per lane), loaded
// once from global (L2-resident). Per-row operand is a wave-uniform s_load.
// partial[blockIdx.x] = block's min.
// ---------------------------------------------------------------------------
__global__ __launch_bounds__(256) void k_min(const float* __restrict__ emb,
                                             const float* __restrict__ alphap,
                                             float* __restrict__ partial) {
    const int b = blockIdx.x >> 5;
    const int chunk = blockIdx.x & 31;
    const int tid = threadIdx.x, wid = tid >> 6, lane = tid & 63;
    const float* e = emb + (size_t)b * FF * NN;
    const float a2 = 2.0f * alphap[0];

    // register-resident j-tile: 16 js per lane (4 float4 chunks x 6 features)
    float4 q[FF][4];
    float pj[16];
    #pragma unroll
    for (int k = 0; k < 4; ++k) {
        const int j0 = k * 256 + lane * 4;
        #pragma unroll
        for (int f = 0; f < FF; ++f) q[f][k] = *(const float4*)(e + f * NN + j0);
    }
    #pragma unroll
    for (int k = 0; k < 4; ++k)
        #pragma unroll
        for (int c = 0; c < 4; ++c) {
            float m = ((const float*)&q[4][k])[c];
            pj[k * 4 + c] = expf(a2 * logf(m));   // momentum^(2*alpha)
        }

    float vmin = 3.4e38f;
    for (int r = 0; r < 8; ++r) {
        const int i = chunk * 32 + wid * 8 + r;
        const int iu = __builtin_amdgcn_readfirstlane(i);  // wave-uniform -> s_load
        float eif[FF];
        #pragma unroll
        for (int f = 0; f < FF; ++f) eif[f] = e[f * NN + iu];
        const float pmi = expf(a2 * logf(eif[4]));
        const int kmin = iu >> 8;   // chunks entirely j<i are skipped (uniform)
        #pragma unroll
        for (int k = 0; k < 4; ++k) {
            if (k >= kmin) {
                #pragma unroll
                for (int c = 0; c < 4; ++c) {
                    float acc = 0.0f;
                    #pragma unroll
                    for (int f = 0; f < FF; ++f) {
                        float t = ((const float*)&q[f][k])[c] - eif[f];
                        acc = fmaf(t, t, acc);   // no-cancellation form
                    }
                    float dd = acc * fminf(pmi, pj[k * 4 + c]);
                    const int j = k * 256 + lane * 4 + c;
                    vmin = (j > i) ? fminf(vmin, dd) : vmin;  // strict upper triangle
                }
            }
        }
    }
    #pragma unroll
    for (int o = 32; o >= 1; o >>= 1) vmin = fminf(vmin, __shfl_xor(vmin, o));
    __shared__ float red[4];
    if (lane == 0) red[wid] = vmin;
    __syncthreads();
    if (tid == 0)
        partial[blockIdx.x] = fminf(fminf(red[0], red[1]), fminf(red[2], red[3]));
}

// ---------------------------------------------------------------------------
// Pass 2: recompute d row-by-row (j-tile in registers), row-softmax, store.
// grid = BB*32 blocks, 256 threads = 4 waves, wave owns 8 rows.
// Diagonal handled as +inf -> exp underflows to exact 0 (matches reference,
// where exp(-beta^2*(1000*max-dmin)/dmin) <= exp(-999) == 0 in fp32/fp64).
// ---------------------------------------------------------------------------
__global__ __launch_bounds__(256) void k_soft(const float* __restrict__ emb,
                                              const float* __restrict__ alphap,
                                              const float* __restrict__ betap,
                                              const float* __restrict__ partial,
                                              float* __restrict__ out) {
    const int b = blockIdx.x >> 5;
    const int chunk = blockIdx.x & 31;
    const int tid = threadIdx.x, wid = tid >> 6, lane = tid & 63;
    const float* e = emb + (size_t)b * FF * NN;
    const float a2 = 2.0f * alphap[0];

    // batch dmin: reduce 32 per-block partials
    __shared__ float s_dmin;
    if (tid < 32) {
        float v = partial[b * 32 + tid];
        #pragma unroll
        for (int o = 16; o >= 1; o >>= 1) v = fminf(v, __shfl_xor(v, o));
        if (tid == 0) s_dmin = v;
    }

    float4 q[FF][4];
    float pj[16];
    #pragma unroll
    for (int k = 0; k < 4; ++k) {
        const int j0 = k * 256 + lane * 4;
        #pragma unroll
        for (int f = 0; f < FF; ++f) q[f][k] = *(const float4*)(e + f * NN + j0);
    }
    #pragma unroll
    for (int k = 0; k < 4; ++k)
        #pragma unroll
        for (int c = 0; c < 4; ++c) {
            float m = ((const float*)&q[4][k])[c];
            pj[k * 4 + c] = expf(a2 * logf(m));
        }
    __syncthreads();
    const float dmin = s_dmin;
    const float beta = betap[0];
    const float s = beta * beta / dmin;   // exponent scale

    for (int r = 0; r < 8; ++r) {
        const int i = chunk * 32 + wid * 8 + r;
        const int iu = __builtin_amdgcn_readfirstlane(i);
        float eif[FF];
        #pragma unroll
        for (int f = 0; f < FF; ++f) eif[f] = e[f * NN + iu];
        const float pmi = expf(a2 * logf(eif[4]));

        float d[16];
        #pragma unroll
        for (int k = 0; k < 4; ++k)
            #pragma unroll
            for (int c = 0; c < 4; ++c) {
                float acc = 0.0f;
                #pragma unroll
                for (int f = 0; f < FF; ++f) {
                    float t = ((const float*)&q[f][k])[c] - eif[f];
                    acc = fmaf(t, t, acc);
                }
                float dd = acc * fminf(pmi, pj[k * 4 + c]);
                const int j = k * 256 + lane * 4 + c;
                d[k * 4 + c] = (j == i) ? __builtin_inff() : dd;
            }

        // row min (softmax shift); diagonal's +inf never wins
        float rmin = d[0];
        #pragma unroll
        for (int t = 1; t < 16; ++t) rmin = fminf(rmin, d[t]);
        #pragma unroll
        for (int o = 32; o >= 1; o >>= 1) rmin = fminf(rmin, __shfl_xor(rmin, o));

        float sum = 0.0f;
        #pragma unroll
        for (int t = 0; t < 16; ++t) {
            float p = __expf(-s * (d[t] - rmin));   // diag: exp(-inf) = 0
            d[t] = p;
            sum += p;
        }
        #pragma unroll
        for (int o = 32; o >= 1; o >>= 1) sum += __shfl_xor(sum, o);
        const float inv = 1.0f / sum;

        float* op = out + ((size_t)b * NN + (size_t)i) * NN;
        #pragma unroll
        for (int k = 0; k < 4; ++k) {
            const int j0 = k * 256 + lane * 4;
            float4 w;
            w.x = d[k * 4 + 0] * inv;
            w.y = d[k * 4 + 1] * inv;
            w.z = d[k * 4 + 2] * inv;
            w.w = d[k * 4 + 3] * inv;
            *(float4*)&op[j0] = w;
        }
    }
}

extern "C" void kernel_launch(void* const* d_in, const int* in_sizes, int n_in,
                              void* d_out, int out_size, void* d_ws, size_t ws_size,
                              hipStream_t stream) {
    const float* emb   = (const float*)d_in[0];
    const float* alpha = (const float*)d_in[1];
    const float* beta  = (const float*)d_in[2];
    float* out = (float*)d_out;
    float* partial = (float*)d_ws;   // BB*32 floats, fully written by k_min each call

    k_min<<<BB * 32, 256, 0, stream>>>(emb, alpha, partial);
    k_soft<<<BB * 32, 256, 0, stream>>>(emb, alpha, beta, partial, out);
}

// Round 3
// 51.907 us; speedup vs baseline: 1.3750x; 1.0973x over previous
//
#include <hip/hip_runtime.h>
#include <math.h>

#define BB 32
#define FF 6
#define NN 1024

// ws layout: [0 .. BB*NN)            pm[b][j] = momentum^(2*alpha)  (128 KB)
//            [BB*NN .. BB*NN+BB*32)  per-block partial mins (4 KB)

// ---------------------------------------------------------------------------
// Pass 0: pm[b][j] = exp(2*alpha*log(emb[b][4][j])) — 32K precise pows, once.
// ---------------------------------------------------------------------------
__global__ void k_pm(const float* __restrict__ emb,
                     const float* __restrict__ alphap,
                     float* __restrict__ pm) {
    const int b = blockIdx.x;
    const int j = threadIdx.x * 4;
    const float a2 = 2.0f * alphap[0];
    float4 v = *(const float4*)(emb + (size_t)b * FF * NN + 4 * NN + j);
    float4 r;
    r.x = expf(a2 * logf(v.x));
    r.y = expf(a2 * logf(v.y));
    r.z = expf(a2 * logf(v.z));
    r.w = expf(a2 * logf(v.w));
    *(float4*)(pm + b * NN + j) = r;
}

// ---------------------------------------------------------------------------
// Pass 1: per-block partial min of strict-upper-triangle d_ij.
// grid = BB*32, 256 threads = 4 waves. Balanced striding: wave wid's rows are
// i = chunk + 32*(r*4+wid) -> each wave sees kmin = {0,0,1,1,2,2,3,3}.
// j-tile (6 features + pm) register-resident, 16 js/lane.
// ---------------------------------------------------------------------------
__global__ __launch_bounds__(256) void k_min(const float* __restrict__ emb,
                                             const float* __restrict__ pm,
                                             float* __restrict__ partial) {
    const int b = blockIdx.x >> 5;
    const int chunk = blockIdx.x & 31;
    const int tid = threadIdx.x, wid = tid >> 6, lane = tid & 63;
    const float* e = emb + (size_t)b * FF * NN;
    const float* pmb = pm + b * NN;

    float4 q[FF][4];
    float pj[16];
    #pragma unroll
    for (int k = 0; k < 4; ++k) {
        const int j0 = k * 256 + lane * 4;
        #pragma unroll
        for (int f = 0; f < FF; ++f) q[f][k] = *(const float4*)(e + f * NN + j0);
        float4 t = *(const float4*)(pmb + j0);
        pj[k * 4 + 0] = t.x; pj[k * 4 + 1] = t.y;
        pj[k * 4 + 2] = t.z; pj[k * 4 + 3] = t.w;
    }

    float vmin = 3.4e38f;
    for (int r = 0; r < 8; ++r) {
        const int i = chunk + 32 * (r * 4 + wid);
        const int iu = __builtin_amdgcn_readfirstlane(i);   // wave-uniform -> s_load
        float eif[FF];
        #pragma unroll
        for (int f = 0; f < FF; ++f) eif[f] = e[f * NN + iu];
        const float pmi = pmb[iu];
        const int kmin = iu >> 8;
        #pragma unroll
        for (int k = 0; k < 4; ++k) {
            if (k >= kmin) {
                #pragma unroll
                for (int c = 0; c < 4; ++c) {
                    float acc = 0.0f;
                    #pragma unroll
                    for (int f = 0; f < FF; ++f) {
                        float t = ((const float*)&q[f][k])[c] - eif[f];
                        acc = fmaf(t, t, acc);   // no-cancellation form
                    }
                    float dd = acc * fminf(pmi, pj[k * 4 + c]);
                    if (k == kmin) {
                        const int j = k * 256 + lane * 4 + c;
                        vmin = (j > iu) ? fminf(vmin, dd) : vmin;
                    } else {
                        vmin = fminf(vmin, dd);   // whole chunk is j > i
                    }
                }
            }
        }
    }
    #pragma unroll
    for (int o = 32; o >= 1; o >>= 1) vmin = fminf(vmin, __shfl_xor(vmin, o));
    __shared__ float red[4];
    if (lane == 0) red[wid] = vmin;
    __syncthreads();
    if (tid == 0)
        partial[blockIdx.x] = fminf(fminf(red[0], red[1]), fminf(red[2], red[3]));
}

// ---------------------------------------------------------------------------
// Pass 2: recompute d (j-tile in registers), row-softmax, coalesced stores.
// Diagonal = +inf -> exp2(-inf) = exact 0 (matches reference: exp(<=-999)==0).
// ---------------------------------------------------------------------------
__global__ __launch_bounds__(256) void k_soft(const float* __restrict__ emb,
                                              const float* __restrict__ pm,
                                              const float* __restrict__ betap,
                                              const float* __restrict__ partial,
                                              float* __restrict__ out) {
    const int b = blockIdx.x >> 5;
    const int chunk = blockIdx.x & 31;
    const int tid = threadIdx.x, wid = tid >> 6, lane = tid & 63;
    const float* e = emb + (size_t)b * FF * NN;
    const float* pmb = pm + b * NN;

    __shared__ float s_dmin;
    if (tid < 32) {
        float v = partial[b * 32 + tid];
        #pragma unroll
        for (int o = 16; o >= 1; o >>= 1) v = fminf(v, __shfl_xor(v, o));
        if (tid == 0) s_dmin = v;
    }

    float4 q[FF][4];
    float pj[16];
    #pragma unroll
    for (int k = 0; k < 4; ++k) {
        const int j0 = k * 256 + lane * 4;
        #pragma unroll
        for (int f = 0; f < FF; ++f) q[f][k] = *(const float4*)(e + f * NN + j0);
        float4 t = *(const float4*)(pmb + j0);
        pj[k * 4 + 0] = t.x; pj[k * 4 + 1] = t.y;
        pj[k * 4 + 2] = t.z; pj[k * 4 + 3] = t.w;
    }
    __syncthreads();
    const float beta = betap[0];
    // exponent scale with log2(e) pre-folded: p = exp2(-s2*(d - rmin))
    const float s2 = beta * beta / s_dmin * 1.4426950408889634f;

    for (int r = 0; r < 8; ++r) {
        const int i = chunk * 32 + wid * 8 + r;
        const int iu = __builtin_amdgcn_readfirstlane(i);
        float eif[FF];
        #pragma unroll
        for (int f = 0; f < FF; ++f) eif[f] = e[f * NN + iu];
        const float pmi = pmb[iu];

        float d[16];
        #pragma unroll
        for (int k = 0; k < 4; ++k)
            #pragma unroll
            for (int c = 0; c < 4; ++c) {
                float acc = 0.0f;
                #pragma unroll
                for (int f = 0; f < FF; ++f) {
                    float t = ((const float*)&q[f][k])[c] - eif[f];
                    acc = fmaf(t, t, acc);
                }
                float dd = acc * fminf(pmi, pj[k * 4 + c]);
                const int j = k * 256 + lane * 4 + c;
                d[k * 4 + c] = (j == iu) ? __builtin_inff() : dd;
            }

        float rmin = d[0];
        #pragma unroll
        for (int t = 1; t < 16; ++t) rmin = fminf(rmin, d[t]);
        #pragma unroll
        for (int o = 32; o >= 1; o >>= 1) rmin = fminf(rmin, __shfl_xor(rmin, o));

        float sum = 0.0f;
        #pragma unroll
        for (int t = 0; t < 16; ++t) {
            float p = __builtin_amdgcn_exp2f(-s2 * (d[t] - rmin));  // diag -> 0
            d[t] = p;
            sum += p;
        }
        #pragma unroll
        for (int o = 32; o >= 1; o >>= 1) sum += __shfl_xor(sum, o);
        const float inv = 1.0f / sum;

        float* op = out + ((size_t)b * NN + (size_t)i) * NN;
        #pragma unroll
        for (int k = 0; k < 4; ++k) {
            const int j0 = k * 256 + lane * 4;
            float4 w;
            w.x = d[k * 4 + 0] * inv;
            w.y = d[k * 4 + 1] * inv;
            w.z = d[k * 4 + 2] * inv;
            w.w = d[k * 4 + 3] * inv;
            *(float4*)&op[j0] = w;
        }
    }
}

extern "C" void kernel_launch(void* const* d_in, const int* in_sizes, int n_in,
                              void* d_out, int out_size, void* d_ws, size_t ws_size,
                              hipStream_t stream) {
    const float* emb   = (const float*)d_in[0];
    const float* alpha = (const float*)d_in[1];
    const float* beta  = (const float*)d_in[2];
    float* out = (float*)d_out;
    float* pm = (float*)d_ws;                 // BB*NN floats
    float* partial = pm + BB * NN;            // BB*32 floats

    k_pm  <<<BB,      256, 0, stream>>>(emb, alpha, pm);
    k_min <<<BB * 32, 256, 0, stream>>>(emb, pm, partial);
    k_soft<<<BB * 32, 256, 0, stream>>>(emb, pm, beta, partial, out);
}